// Round 1
// baseline (671.619 us; speedup 1.0000x reference)
//
#include <hip/hip_runtime.h>
#include <hip/hip_bf16.h>

typedef __attribute__((ext_vector_type(8))) short short8;
typedef __attribute__((ext_vector_type(4))) float f32x4;
typedef unsigned short u16;

#define S_LEN 2048
#define D_DIM 2048
#define NHEAD 16
#define HDIM 128
#define M_ROWS 4096

#define MFMA(a,b,c) __builtin_amdgcn_mfma_f32_16x16x32_bf16(a,b,c,0,0,0)

__device__ __forceinline__ u16 f2bf(float f) {
  union { float f; unsigned u; } v; v.f = f;
  unsigned r = v.u + 0x7fffu + ((v.u >> 16) & 1u);
  return (u16)(r >> 16);
}

__device__ __forceinline__ void async16(void* lds, const void* g) {
  __builtin_amdgcn_global_load_lds(
      (const __attribute__((address_space(1))) unsigned*)g,
      (__attribute__((address_space(3))) unsigned*)lds, 16, 0, 0);
}

// ---------------- x -> bf16 ----------------
__global__ void k_cvt_x(const float* __restrict__ x, u16* __restrict__ xb) {
  int i = blockIdx.x * 256 + threadIdx.x;
  float4 v = reinterpret_cast<const float4*>(x)[i];
  ushort4 o;
  o.x = f2bf(v.x); o.y = f2bf(v.y); o.z = f2bf(v.z); o.w = f2bf(v.w);
  reinterpret_cast<ushort4*>(xb)[i] = o;
}

// -------- W[k][n] f32 -> Wt[n][k] bf16 (transpose+convert) --------
__global__ void k_cvt_wt(const float* __restrict__ W, u16* __restrict__ Wt) {
  __shared__ u16 tile[32][33];
  int n0 = blockIdx.x * 32, k0 = blockIdx.y * 32;
  int tx = threadIdx.x & 31, ty = threadIdx.x >> 5;
#pragma unroll
  for (int i = 0; i < 4; i++)
    tile[ty + i * 8][tx] = f2bf(W[(size_t)(k0 + ty + i * 8) * D_DIM + n0 + tx]);
  __syncthreads();
#pragma unroll
  for (int i = 0; i < 4; i++)
    Wt[(size_t)(n0 + ty + i * 8) * D_DIM + k0 + tx] = tile[tx][ty + i * 8];
}

// -------- V[b,h,s,d] -> Vt[b,h,d,s] (bf16 transpose) --------
__global__ void k_vtrans(const u16* __restrict__ V, u16* __restrict__ Vt) {
  __shared__ u16 tile[32][33];
  int s0 = blockIdx.x * 32, d0 = blockIdx.y * 32, bh = blockIdx.z;
  const u16* Vp = V + (size_t)bh * S_LEN * HDIM;
  u16* Vtp = Vt + (size_t)bh * HDIM * S_LEN;
  int tx = threadIdx.x & 31, ty = threadIdx.x >> 5;
#pragma unroll
  for (int i = 0; i < 4; i++)
    tile[ty + i * 8][tx] = Vp[(size_t)(s0 + ty + i * 8) * HDIM + d0 + tx];
  __syncthreads();
#pragma unroll
  for (int i = 0; i < 4; i++)
    Vtp[(size_t)(d0 + ty + i * 8) * S_LEN + s0 + tx] = tile[tx][ty + i * 8];
}

// -------- GEMM: C[M][N] = A[M][K] * Bt[N][K]^T, 128x128 tile, 4 waves --------
// MODE 0: write bf16 scattered into [b,h,s,hd]
// MODE 1: write f32 row-major with phase factor
template <int MODE>
__global__ __launch_bounds__(256) void k_gemm(const u16* __restrict__ A,
                                              const u16* __restrict__ Bt,
                                              void* __restrict__ outp,
                                              const float* __restrict__ fac) {
  __shared__ u16 As[128 * 32];
  __shared__ u16 Bs[128 * 32];
  const int m0 = blockIdx.y * 128, n0 = blockIdx.x * 128;
  const int t = threadIdx.x;
  const int w = t >> 6, l = t & 63;
  const int wr = (w >> 1) * 64, wc = (w & 1) * 64;
  const int lr = l & 15, lk = (l >> 4) * 8;
  f32x4 acc[4][4] = {};

  for (int k0 = 0; k0 < D_DIM; k0 += 32) {
#pragma unroll
    for (int i = 0; i < 2; i++) {
      const int ib = i * 256 + w * 64;
      const int idx = ib + l;
      const int row = idx >> 2, kq = idx & 3;
      async16(As + ib * 8, A + (size_t)(m0 + row) * D_DIM + k0 + kq * 8);
      async16(Bs + ib * 8, Bt + (size_t)(n0 + row) * D_DIM + k0 + kq * 8);
    }
    __syncthreads();
    short8 af[4], bfr[4];
#pragma unroll
    for (int mi = 0; mi < 4; mi++)
      af[mi] = *reinterpret_cast<const short8*>(As + (wr + mi * 16 + lr) * 32 + lk);
#pragma unroll
    for (int ni = 0; ni < 4; ni++)
      bfr[ni] = *reinterpret_cast<const short8*>(Bs + (wc + ni * 16 + lr) * 32 + lk);
#pragma unroll
    for (int mi = 0; mi < 4; mi++)
#pragma unroll
      for (int ni = 0; ni < 4; ni++)
        acc[mi][ni] = MFMA(af[mi], bfr[ni], acc[mi][ni]);
    __syncthreads();
  }

#pragma unroll
  for (int mi = 0; mi < 4; mi++) {
#pragma unroll
    for (int ni = 0; ni < 4; ni++) {
#pragma unroll
      for (int r = 0; r < 4; r++) {
        const int row = m0 + wr + mi * 16 + (l >> 4) * 4 + r;
        const int col = n0 + wc + ni * 16 + lr;
        float v = acc[mi][ni][r];
        if (MODE == 0) {
          ((u16*)outp)[(((size_t)((row >> 11) * NHEAD + (col >> 7))) * S_LEN +
                        (row & 2047)) * HDIM + (col & 127)] = f2bf(v);
        } else {
          ((float*)outp)[(size_t)row * D_DIM + col] = v * (1.0f + 0.1f * fac[row]);
        }
      }
    }
  }
}

// -------- phase projections pq/pk = x @ Wpq / x @ Wpk (f32) --------
__global__ __launch_bounds__(64) void k_phase_proj(const float* __restrict__ x,
                                                   const float* __restrict__ Wpq,
                                                   const float* __restrict__ Wpk,
                                                   float* __restrict__ pq,
                                                   float* __restrict__ pk) {
  int m = blockIdx.x;
  int l = threadIdx.x;
  int h = l & 15, part = l >> 4;
  const float* xr = x + (size_t)m * D_DIM + part * 512;
  float sq = 0.f, sk = 0.f;
  for (int k = 0; k < 512; k++) {
    float xv = xr[k];
    int kk = part * 512 + k;
    sq += xv * Wpq[(size_t)kk * NHEAD + h];
    sk += xv * Wpk[(size_t)kk * NHEAD + h];
  }
  sq += __shfl_xor(sq, 16); sq += __shfl_xor(sq, 32);
  sk += __shfl_xor(sk, 16); sk += __shfl_xor(sk, 32);
  if (l < 16) {
    pq[(size_t)m * NHEAD + l] = sq;
    pk[(size_t)m * NHEAD + l] = sk;
  }
}

__device__ __forceinline__ float wave_sum(float v) {
  v += __shfl_xor(v, 1);  v += __shfl_xor(v, 2);  v += __shfl_xor(v, 4);
  v += __shfl_xor(v, 8);  v += __shfl_xor(v, 16); v += __shfl_xor(v, 32);
  return v;
}

// -------- Ck/Sk = sum_s cos/sin(pk) per (b,h) --------
__global__ void k_phase_ck(const float* __restrict__ pk, float* __restrict__ Ck,
                           float* __restrict__ Sk) {
  int bh = blockIdx.x, b = bh >> 4, h = bh & 15;
  float c = 0.f, s = 0.f;
  for (int ss = threadIdx.x; ss < S_LEN; ss += 256) {
    float v = pk[((size_t)b * S_LEN + ss) * NHEAD + h];
    c += cosf(v); s += sinf(v);
  }
  c = wave_sum(c); s = wave_sum(s);
  __shared__ float rc[4], rs[4];
  int wv = threadIdx.x >> 6;
  if ((threadIdx.x & 63) == 0) { rc[wv] = c; rs[wv] = s; }
  __syncthreads();
  if (threadIdx.x == 0) {
    Ck[bh] = rc[0] + rc[1] + rc[2] + rc[3];
    Sk[bh] = rs[0] + rs[1] + rs[2] + rs[3];
  }
}

// -------- phase_mod[m] --------
__global__ void k_phase_mod(const float* __restrict__ pq, const float* __restrict__ Ck,
                            const float* __restrict__ Sk, float* __restrict__ pm) {
  int m = blockIdx.x * 256 + threadIdx.x;
  int b = m >> 11;
  float a = 0.f;
#pragma unroll
  for (int h = 0; h < NHEAD; h++) {
    float v = pq[(size_t)m * NHEAD + h];
    a += cosf(v) * Ck[b * NHEAD + h] + sinf(v) * Sk[b * NHEAD + h];
  }
  pm[m] = a * (1.0f / (S_LEN * NHEAD));
}

// -------- causal flash attention: 1 wave per 16 q-rows --------
__global__ __launch_bounds__(64) void k_attn(const u16* __restrict__ Q,
                                             const u16* __restrict__ K,
                                             const u16* __restrict__ Vt,
                                             u16* __restrict__ ctx) {
  const int qt = blockIdx.x, bh = blockIdx.y;
  const int b = bh >> 4, h = bh & 15;
  const int q0 = qt * 16;
  const int l = threadIdx.x;
  const int lr = l & 15, lg = l >> 4, lk = lg * 8;
  const u16* Qp = Q + (size_t)bh * S_LEN * HDIM;
  const u16* Kp = K + (size_t)bh * S_LEN * HDIM;
  const u16* Vp = Vt + (size_t)bh * HDIM * S_LEN;
  short8 qf[4];
#pragma unroll
  for (int c = 0; c < 4; c++)
    qf[c] = *reinterpret_cast<const short8*>(Qp + (size_t)(q0 + lr) * HDIM + c * 32 + lk);
  f32x4 o[8] = {};
  float mrun[4] = {-1e30f, -1e30f, -1e30f, -1e30f};
  float lrun[4] = {0.f, 0.f, 0.f, 0.f};
  __shared__ u16 P[16 * 32];
  const float scale = 0.08838834764831845f;

  for (int k0 = 0; k0 < q0 + 16; k0 += 32) {
    f32x4 s0 = {}, s1 = {};
#pragma unroll
    for (int c = 0; c < 4; c++) {
      short8 kf0 = *reinterpret_cast<const short8*>(Kp + (size_t)(k0 + lr) * HDIM + c * 32 + lk);
      short8 kf1 = *reinterpret_cast<const short8*>(Kp + (size_t)(k0 + 16 + lr) * HDIM + c * 32 + lk);
      s0 = MFMA(qf[c], kf0, s0);
      s1 = MFMA(qf[c], kf1, s1);
    }
    float fres[4];
#pragma unroll
    for (int r = 0; r < 4; r++) {
      const int qq = q0 + lg * 4 + r;
      float v0 = (k0 + lr <= qq) ? s0[r] * scale : -1e30f;
      float v1 = (k0 + 16 + lr <= qq) ? s1[r] * scale : -1e30f;
      float mx = fmaxf(v0, v1);
      mx = fmaxf(mx, __shfl_xor(mx, 1));
      mx = fmaxf(mx, __shfl_xor(mx, 2));
      mx = fmaxf(mx, __shfl_xor(mx, 4));
      mx = fmaxf(mx, __shfl_xor(mx, 8));
      const float nm = fmaxf(mrun[r], mx);
      const float f = __expf(mrun[r] - nm);
      const float p0 = __expf(v0 - nm), p1 = __expf(v1 - nm);
      float rsum = p0 + p1;
      rsum += __shfl_xor(rsum, 1);
      rsum += __shfl_xor(rsum, 2);
      rsum += __shfl_xor(rsum, 4);
      rsum += __shfl_xor(rsum, 8);
      lrun[r] = lrun[r] * f + rsum;
      mrun[r] = nm;
      fres[r] = f;
      P[(lg * 4 + r) * 32 + lr] = f2bf(p0);
      P[(lg * 4 + r) * 32 + 16 + lr] = f2bf(p1);
    }
#pragma unroll
    for (int d = 0; d < 8; d++)
#pragma unroll
      for (int r = 0; r < 4; r++) o[d][r] *= fres[r];
    __syncthreads();
    const short8 pa = *reinterpret_cast<const short8*>(P + lr * 32 + lk);
#pragma unroll
    for (int d = 0; d < 8; d++) {
      short8 vf = *reinterpret_cast<const short8*>(Vp + (size_t)(d * 16 + lr) * S_LEN + k0 + lk);
      o[d] = MFMA(pa, vf, o[d]);
    }
    __syncthreads();
  }

#pragma unroll
  for (int d = 0; d < 8; d++) {
#pragma unroll
    for (int r = 0; r < 4; r++) {
      const int qq = q0 + lg * 4 + r;
      float v = o[d][r] / lrun[r];
      ctx[((size_t)(b * S_LEN + qq)) * D_DIM + h * HDIM + d * 16 + lr] = f2bf(v);
    }
  }
}

extern "C" void kernel_launch(void* const* d_in, const int* in_sizes, int n_in,
                              void* d_out, int out_size, void* d_ws, size_t ws_size,
                              hipStream_t stream) {
  const float* x   = (const float*)d_in[0];
  const float* Wq  = (const float*)d_in[1];
  const float* Wk  = (const float*)d_in[2];
  const float* Wv  = (const float*)d_in[3];
  const float* Wo  = (const float*)d_in[4];
  const float* Wpq = (const float*)d_in[5];
  const float* Wpk = (const float*)d_in[6];

  char* ws = (char*)d_ws;
  u16* xb   = (u16*)(ws + 0);            // 16 MB  x bf16 [4096][2048]
  u16* Wqt  = (u16*)(ws + 16777216);     // 8 MB each, transposed bf16
  u16* Wkt  = (u16*)(ws + 25165824);
  u16* Wvt  = (u16*)(ws + 33554432);
  u16* Wot  = (u16*)(ws + 41943040);
  u16* Qb   = (u16*)(ws + 50331648);     // [b,h,s,d] bf16
  u16* Kb   = (u16*)(ws + 67108864);
  u16* Vb   = (u16*)(ws + 83886080);     // V, later reused as ctx
  u16* Vt   = (u16*)(ws + 100663296);    // [b,h,d,s] bf16
  float* pq = (float*)(ws + 117440512);
  float* pk = (float*)(ws + 117702656);
  float* Ck = (float*)(ws + 117964800);
  float* Sk = (float*)(ws + 117964928);
  float* pm = (float*)(ws + 117965056);

  k_cvt_x<<<dim3(M_ROWS * D_DIM / 1024), 256, 0, stream>>>(x, xb);
  k_cvt_wt<<<dim3(64, 64), 256, 0, stream>>>(Wq, Wqt);
  k_cvt_wt<<<dim3(64, 64), 256, 0, stream>>>(Wk, Wkt);
  k_cvt_wt<<<dim3(64, 64), 256, 0, stream>>>(Wv, Wvt);
  k_cvt_wt<<<dim3(64, 64), 256, 0, stream>>>(Wo, Wot);

  k_gemm<0><<<dim3(16, 32), 256, 0, stream>>>(xb, Wqt, Qb, nullptr);
  k_gemm<0><<<dim3(16, 32), 256, 0, stream>>>(xb, Wkt, Kb, nullptr);
  k_gemm<0><<<dim3(16, 32), 256, 0, stream>>>(xb, Wvt, Vb, nullptr);

  k_vtrans<<<dim3(64, 4, 32), 256, 0, stream>>>(Vb, Vt);

  k_phase_proj<<<dim3(M_ROWS), 64, 0, stream>>>(x, Wpq, Wpk, pq, pk);
  k_phase_ck<<<dim3(32), 256, 0, stream>>>(pk, Ck, Sk);
  k_phase_mod<<<dim3(16), 256, 0, stream>>>(pq, Ck, Sk, pm);

  k_attn<<<dim3(128, 32), 64, 0, stream>>>(Qb, Kb, Vt, Vb /*ctx*/);

  k_gemm<1><<<dim3(16, 32), 256, 0, stream>>>(Vb /*ctx*/, Wot, (void*)d_out, pm);
}